// Round 4
// baseline (5557.607 us; speedup 1.0000x reference)
//
#include <hip/hip_runtime.h>
#include <stdint.h>

typedef unsigned int uint;
typedef unsigned short ushort;
typedef unsigned char uchar;
typedef __attribute__((ext_vector_type(8))) short bf16x8;
typedef __attribute__((ext_vector_type(4))) float f32x4;

__device__ __forceinline__ ushort f2bf(float f) {
  uint u = __builtin_bit_cast(uint, f);
  return (ushort)((u + 0x7FFFu + ((u >> 16) & 1u)) >> 16);
}

// ---------------------------------------------------------------------------
// Mask element width: esz stays nonzero if every sampled 4-byte word is in
// {0,1,0x3F800000} (int32/float32 masks); byte masks fail with certainty.
__global__ __launch_bounds__(256) void k_detect(
    const uint* __restrict__ mp, const uint* __restrict__ ms,
    const uint* __restrict__ mt, int* __restrict__ esz) {
  int bid = blockIdx.x;  // 192 blocks: 3 masks x 64 chunks
  const uint* m = (bid < 64) ? mp : (bid < 128) ? ms : mt;
  uint v = m[(size_t)(bid & 63) * 65521 + threadIdx.x];
  if (!(v == 0u || v == 1u || v == 0x3F800000u)) atomicAnd(esz, 0);
}

// ---------------------------------------------------------------------------
// Streaming mask compression: one wave per (mid,row). Reads 8KB (int32) or
// 2KB (byte) coalesced, writes 256B bitmap + inv/ind scalars. BW-bound.
__global__ __launch_bounds__(256) void k_pack(
    const void* __restrict__ mp, const void* __restrict__ ms,
    const void* __restrict__ mt, uint* __restrict__ bm,
    float* __restrict__ inv, float* __restrict__ ind,
    const int* __restrict__ esz_p) {
  const int gid = blockIdx.x * 4 + (threadIdx.x >> 6);  // 49152 rows
  const int lane = threadIdx.x & 63;
  const int mid = gid >> 14;
  const int row = gid & 16383;
  const void* mask = (mid == 0) ? mp : (mid == 1) ? ms : mt;
  const bool is4 = (*esz_p != 0);
  uint w = 0;
  if (is4) {
    const uint* p = (const uint*)mask + (size_t)row * 2048 + lane * 32;
    uint4 v[8];
#pragma unroll
    for (int q = 0; q < 8; ++q) v[q] = *(const uint4*)(p + q * 4);
#pragma unroll
    for (int q = 0; q < 8; ++q) {
      w |= (v[q].x != 0u ? 1u : 0u) << (q * 4 + 0);
      w |= (v[q].y != 0u ? 1u : 0u) << (q * 4 + 1);
      w |= (v[q].z != 0u ? 1u : 0u) << (q * 4 + 2);
      w |= (v[q].w != 0u ? 1u : 0u) << (q * 4 + 3);
    }
  } else {
    const uchar* p = (const uchar*)mask + (size_t)row * 2048 + lane * 32;
    uint4 v0 = *(const uint4*)p;
    uint4 v1 = *(const uint4*)(p + 16);
    uint arr[8] = {v0.x, v0.y, v0.z, v0.w, v1.x, v1.y, v1.z, v1.w};
#pragma unroll
    for (int q = 0; q < 8; ++q)
#pragma unroll
      for (int j = 0; j < 4; ++j)
        w |= (((arr[q] >> (j * 8)) & 0xFFu) ? 1u : 0u) << (q * 4 + j);
  }
  bm[(size_t)gid * 64 + lane] = w;
  int c = __popc(w);
#pragma unroll
  for (int off = 1; off < 64; off <<= 1) c += __shfl_xor(c, off, 64);
  if (lane == 0) {
    inv[gid] = 1.0f / (float)(c > 0 ? c : 1);
    ind[gid] = (c > 0) ? 1.0f : 0.0f;
  }
}

// ---------------------------------------------------------------------------
// Fused-weight stage 1: T1 = W_space @ W_mix[0:128], T2 = W_same @ W_mix[128:256]
__global__ __launch_bounds__(256) void k_fuse1(
    const float* __restrict__ Ws, const float* __restrict__ Wsame,
    const float* __restrict__ Wm, float* __restrict__ T1, float* __restrict__ T2) {
  int idx = blockIdx.x * 256 + threadIdx.x;
  if (idx >= 81920) return;
  int r = idx >> 7, n = idx & 127;
  float s = 0.f;
  if (r < 384) {
    for (int c = 0; c < 128; ++c) s += Ws[r * 128 + c] * Wm[c * 128 + n];
    T1[r * 128 + n] = s;
  } else {
    int rr = r - 384;
    for (int c = 0; c < 128; ++c) s += Wsame[rr * 128 + c] * Wm[(128 + c) * 128 + n];
    T2[rr * 128 + n] = s;
  }
}

// ---------------------------------------------------------------------------
// Stage 2: UT[y][n][k] (bf16) for y=0:origin 1:pred 2:succ 3:same, plus
// cvec[0..3][n] bias vectors (c0 includes all constant paths).
__global__ __launch_bounds__(256) void k_fuse2(
    const float* __restrict__ We, const float* __restrict__ be,
    const float* __restrict__ bs, const float* __restrict__ bsame,
    const float* __restrict__ bm_, const float* __restrict__ Wm,
    const float* __restrict__ T1, const float* __restrict__ T2,
    ushort* __restrict__ UT, float* __restrict__ cvec) {
  int idx = blockIdx.x * 256 + threadIdx.x;
  if (idx < 65536) {
    int y = idx >> 14, n = (idx >> 7) & 127, k = idx & 127;
    float s = 0.f;
    if (y == 0)
      for (int m = 0; m < 128; ++m)
        s += We[k * 512 + m] * (T1[(128 + m) * 128 + n] + T2[m * 128 + n]);
    else if (y == 1)
      for (int m = 0; m < 128; ++m) s += We[k * 512 + 128 + m] * T1[m * 128 + n];
    else if (y == 2)
      for (int m = 0; m < 128; ++m) s += We[k * 512 + 256 + m] * T1[(256 + m) * 128 + n];
    else
      for (int m = 0; m < 128; ++m) s += We[k * 512 + 384 + m] * T2[(128 + m) * 128 + n];
    UT[((size_t)y * 128 + n) * 128 + k] = f2bf(s);
  } else if (idx < 66048) {
    int cid = idx - 65536, cv = cid >> 7, n = cid & 127;
    float s = 0.f;
    if (cv == 0) {
      for (int m = 0; m < 128; ++m)
        s += be[m] * (T1[(128 + m) * 128 + n] + T2[m * 128 + n]);
      for (int c = 0; c < 128; ++c) s += bs[c] * Wm[c * 128 + n];
      for (int c = 0; c < 128; ++c) s += bsame[c] * Wm[(128 + c) * 128 + n];
      s += bm_[n];
    } else if (cv == 1) {
      for (int m = 0; m < 128; ++m) s += be[128 + m] * T1[m * 128 + n];
    } else if (cv == 2) {
      for (int m = 0; m < 128; ++m) s += be[256 + m] * T1[(256 + m) * 128 + n];
    } else {
      for (int m = 0; m < 128; ++m) s += be[384 + m] * T2[(128 + m) * 128 + n];
    }
    cvec[cv * 128 + n] = s;
  }
}

// ---------------------------------------------------------------------------
// Encoder: feat(f32) @ UT[y]. y=0 -> out = origin + c0; y=1..3 -> e'_mid in
// MFMA-B-fragment order (16KB tiles, coalesced stores via LDS transpose).
__global__ __launch_bounds__(256) void k_enc(
    const float* __restrict__ feat, const ushort* __restrict__ UT,
    const float* __restrict__ cvec, float* __restrict__ out,
    ushort* __restrict__ eT0, ushort* __restrict__ eT1, ushort* __restrict__ eT2) {
  __shared__ ushort As[64 * 72];
  __shared__ ushort Bs[128 * 72];
  __shared__ ushort stage[8192];
  const int t = threadIdx.x;
  const int gm0 = blockIdx.x * 64;
  const int y = blockIdx.y;
  const int lane = t & 63, wave = t >> 6;
  const int m0w = (wave >> 1) * 32, n0w = (wave & 1) * 64;
  const int quad = lane >> 4, lr = lane & 15;
  const int am = t >> 2, aq = t & 3;
  const int bn = t >> 1, bh = t & 1;
  f32x4 acc[2][4] = {};
  for (int k0 = 0; k0 < 128; k0 += 64) {
    const float* asrc = feat + (size_t)(gm0 + am) * 128 + k0 + aq * 16;
    float4 f0 = *(const float4*)asrc;
    float4 f1 = *(const float4*)(asrc + 4);
    float4 f2 = *(const float4*)(asrc + 8);
    float4 f3 = *(const float4*)(asrc + 12);
    ushort h[16];
    h[0] = f2bf(f0.x); h[1] = f2bf(f0.y); h[2] = f2bf(f0.z); h[3] = f2bf(f0.w);
    h[4] = f2bf(f1.x); h[5] = f2bf(f1.y); h[6] = f2bf(f1.z); h[7] = f2bf(f1.w);
    h[8] = f2bf(f2.x); h[9] = f2bf(f2.y); h[10] = f2bf(f2.z); h[11] = f2bf(f2.w);
    h[12] = f2bf(f3.x); h[13] = f2bf(f3.y); h[14] = f2bf(f3.z); h[15] = f2bf(f3.w);
    const ushort* bsrc = UT + ((size_t)y * 128 + bn) * 128 + k0 + bh * 32;
    bf16x8 bv0 = *(const bf16x8*)bsrc;
    bf16x8 bv1 = *(const bf16x8*)(bsrc + 8);
    bf16x8 bv2 = *(const bf16x8*)(bsrc + 16);
    bf16x8 bv3 = *(const bf16x8*)(bsrc + 24);
    *(bf16x8*)&As[am * 72 + aq * 16] = *(bf16x8*)&h[0];
    *(bf16x8*)&As[am * 72 + aq * 16 + 8] = *(bf16x8*)&h[8];
    *(bf16x8*)&Bs[bn * 72 + bh * 32] = bv0;
    *(bf16x8*)&Bs[bn * 72 + bh * 32 + 8] = bv1;
    *(bf16x8*)&Bs[bn * 72 + bh * 32 + 16] = bv2;
    *(bf16x8*)&Bs[bn * 72 + bh * 32 + 24] = bv3;
    __syncthreads();
#pragma unroll
    for (int kc = 0; kc < 2; ++kc) {
      bf16x8 a[2], b[4];
#pragma unroll
      for (int i = 0; i < 2; ++i)
        a[i] = *(const bf16x8*)&As[(m0w + i * 16 + lr) * 72 + kc * 32 + quad * 8];
#pragma unroll
      for (int j = 0; j < 4; ++j)
        b[j] = *(const bf16x8*)&Bs[(n0w + j * 16 + lr) * 72 + kc * 32 + quad * 8];
#pragma unroll
      for (int i = 0; i < 2; ++i)
#pragma unroll
        for (int j = 0; j < 4; ++j)
          acc[i][j] = __builtin_amdgcn_mfma_f32_16x16x32_bf16(a[i], b[j], acc[i][j], 0, 0, 0);
    }
    __syncthreads();
  }
  if (y == 0) {
#pragma unroll
    for (int i = 0; i < 2; ++i)
#pragma unroll
      for (int j = 0; j < 4; ++j)
#pragma unroll
        for (int r = 0; r < 4; ++r) {
          int m = gm0 + m0w + i * 16 + quad * 4 + r;
          int n = n0w + j * 16 + lr;
          out[(size_t)m * 128 + n] = acc[i][j][r] + cvec[n];
        }
  } else {
#pragma unroll
    for (int i = 0; i < 2; ++i)
#pragma unroll
      for (int j = 0; j < 4; ++j)
#pragma unroll
        for (int r = 0; r < 4; ++r) {
          int rl = m0w + i * 16 + quad * 4 + r;
          int n = n0w + j * 16 + lr;
          int kc = rl >> 5, qd = (rl >> 3) & 3, e = rl & 7;
          stage[((((n >> 4) * 2 + kc) * 4 + qd) * 16 + (n & 15)) * 8 + e] =
              f2bf(acc[i][j][r]);
        }
    __syncthreads();
    ushort* eT = (y == 1) ? eT0 : (y == 2) ? eT1 : eT2;
    ushort* dst = eT + ((size_t)(gm0 >> 11) * 32 + ((gm0 >> 6) & 31)) * 8192 + t * 32;
    const ushort* src = stage + t * 32;
#pragma unroll
    for (int p = 0; p < 4; ++p)
      *(bf16x8*)(dst + p * 8) = *(const bf16x8*)(src + p * 8);
  }
}

// ---------------------------------------------------------------------------
// Masked-mean GEMM from bitmaps. Bitmap staged to LDS (pad-68 stride, 2-way
// max bank aliasing = free). B-frags from L2 with depth-2 register prefetch.
// Epilogue: Pm[row][n] = acc*inv + ind*cm[n], plain coalesced f32 stores.
__global__ __launch_bounds__(256, 3) void k_mm(
    const uint* __restrict__ bm, const ushort* __restrict__ eT0,
    const ushort* __restrict__ eT1, const ushort* __restrict__ eT2,
    const float* __restrict__ inv, const float* __restrict__ ind,
    const float* __restrict__ cvec, float* __restrict__ P0,
    float* __restrict__ P1, float* __restrict__ P2) {
  __shared__ uint sbm[64][68];
  const int t = threadIdx.x;
  const int id = blockIdx.x;
  const int xcd = id & 7, q = id >> 3;
  const int mtile = q & 31, gg = xcd * 3 + (q >> 5);
  const int b = gg & 7, mid = gg >> 3;
  const ushort* eT = (mid == 0) ? eT0 : (mid == 1) ? eT1 : eT2;
  float* Pm = (mid == 0) ? P0 : (mid == 1) ? P1 : P2;
  const float* cm = cvec + (mid + 1) * 128;
  const size_t rowbase = (size_t)b * 2048 + mtile * 64;
  const uint* bmbase = bm + ((size_t)mid * 16384 + rowbase) * 64;
  {  // stage 16KB bitmap: t -> row t>>2, words (t&3)*16 .. +15
    int r = t >> 2, c0 = (t & 3) * 16;
    const uint* src = bmbase + (size_t)r * 64 + c0;
    uint4 v0 = *(const uint4*)src;
    uint4 v1 = *(const uint4*)(src + 4);
    uint4 v2 = *(const uint4*)(src + 8);
    uint4 v3 = *(const uint4*)(src + 12);
    *(uint4*)&sbm[r][c0] = v0;
    *(uint4*)&sbm[r][c0 + 4] = v1;
    *(uint4*)&sbm[r][c0 + 8] = v2;
    *(uint4*)&sbm[r][c0 + 12] = v3;
  }
  const int lane = t & 63, wave = t >> 6;
  const int m0w = (wave >> 1) * 32, n0w = (wave & 1) * 64;
  const int quad = lane >> 4, lr = lane & 15;
  const int jb = n0w >> 4;
  const int r0l = m0w + lr, r1l = r0l + 16;
  const ushort* bbase = eT + (size_t)b * 32 * 8192 + quad * 128 + lr * 8;
  f32x4 acc[2][4] = {};
  bf16x8 pb[2][4];
#pragma unroll
  for (int pi = 0; pi < 2; ++pi) {
    const ushort* bp = bbase + (pi & 1) * 512;  // tiles 0; kc=pi
#pragma unroll
    for (int j = 0; j < 4; ++j) pb[pi][j] = *(const bf16x8*)(bp + (jb + j) * 1024);
  }
  __syncthreads();
  for (int it = 0; it < 64; ++it) {
    const uint w0 = sbm[r0l][it];
    const uint w1 = sbm[r1l][it];
    union { bf16x8 v; uint u[4]; } a0, a1;
    const uint s0 = w0 >> (quad * 8), s1 = w1 >> (quad * 8);
#pragma unroll
    for (int p = 0; p < 4; ++p) {
      a0.u[p] = (((s0 >> (2 * p)) & 1u) ? 0x3F80u : 0u) |
                (((s0 >> (2 * p)) & 2u) ? 0x3F800000u : 0u);
      a1.u[p] = (((s1 >> (2 * p)) & 1u) ? 0x3F80u : 0u) |
                (((s1 >> (2 * p)) & 2u) ? 0x3F800000u : 0u);
    }
    const int cur = it & 1;
#pragma unroll
    for (int j = 0; j < 4; ++j) {
      acc[0][j] = __builtin_amdgcn_mfma_f32_16x16x32_bf16(a0.v, pb[cur][j], acc[0][j], 0, 0, 0);
      acc[1][j] = __builtin_amdgcn_mfma_f32_16x16x32_bf16(a1.v, pb[cur][j], acc[1][j], 0, 0, 0);
    }
    int itn = it + 2;
    if (itn > 63) itn = 63;
    const ushort* bp = bbase + (itn >> 1) * 8192 + (itn & 1) * 512;
#pragma unroll
    for (int j = 0; j < 4; ++j) pb[cur][j] = *(const bf16x8*)(bp + (jb + j) * 1024);
  }
  float cmv[4];
#pragma unroll
  for (int j = 0; j < 4; ++j) cmv[j] = cm[n0w + j * 16 + lr];
#pragma unroll
  for (int i = 0; i < 2; ++i)
#pragma unroll
    for (int r = 0; r < 4; ++r) {
      const int ml = m0w + i * 16 + quad * 4 + r;
      const size_t row = rowbase + ml;
      const float iv = inv[(size_t)mid * 16384 + row];
      const float id_ = ind[(size_t)mid * 16384 + row];
#pragma unroll
      for (int j = 0; j < 4; ++j) {
        const int n = n0w + j * 16 + lr;
        Pm[row * 128 + n] = acc[i][j][r] * iv + id_ * cmv[j];
      }
    }
}

// ---------------------------------------------------------------------------
// Final merge: out(base) += P0 + P1 + P2. Pure streaming.
__global__ __launch_bounds__(256) void k_add(
    float4* __restrict__ out, const float4* __restrict__ P0,
    const float4* __restrict__ P1, const float4* __restrict__ P2) {
  const int i = blockIdx.x * 256 + threadIdx.x;  // 524288 float4s
  float4 o = out[i];
  const float4 a = P0[i], b = P1[i], c = P2[i];
  o.x += a.x + b.x + c.x;
  o.y += a.y + b.y + c.y;
  o.z += a.z + b.z + c.z;
  o.w += a.w + b.w + c.w;
  out[i] = o;
}

// ---------------------------------------------------------------------------
extern "C" void kernel_launch(void* const* d_in, const int* in_sizes, int n_in,
                              void* d_out, int out_size, void* d_ws,
                              size_t ws_size, hipStream_t stream) {
  const float* features = (const float*)d_in[0];
  const void* pred = d_in[1];
  const void* succ = d_in[2];
  const void* same = d_in[3];
  const float* W_enc = (const float*)d_in[4];
  const float* b_enc = (const float*)d_in[5];
  const float* W_space = (const float*)d_in[6];
  const float* b_space = (const float*)d_in[7];
  const float* W_same = (const float*)d_in[8];
  const float* b_same = (const float*)d_in[9];
  const float* W_mix = (const float*)d_in[10];
  const float* b_mix = (const float*)d_in[11];
  float* out = (float*)d_out;

  char* wsb = (char*)d_ws;
  ushort* UT = (ushort*)wsb;                          // 128 KB
  float* cvec = (float*)(wsb + 131072);               // 2 KB
  float* T1 = (float*)(wsb + 133120);                 // 192 KB
  float* T2 = (float*)(wsb + 329728);                 // 128 KB
  ushort* eT0 = (ushort*)(wsb + 460800);              // 4 MB each
  ushort* eT1 = (ushort*)(wsb + 460800 + 4194304);
  ushort* eT2 = (ushort*)(wsb + 460800 + 8388608);
  uint* bm = (uint*)(wsb + 13043712);                 // 12 MB bitmaps
  float* inv = (float*)(wsb + 25626624);              // 192 KB
  float* ind = (float*)(wsb + 25823232);              // 192 KB
  float* P0 = (float*)(wsb + 26019840);               // 8 MB each
  float* P1 = (float*)(wsb + 26019840 + 8388608);
  float* P2 = (float*)(wsb + 26019840 + 16777216);
  int* esz = (int*)(wsb + 51185664);

  hipMemsetAsync(esz, 1, 4, stream);
  k_detect<<<192, 256, 0, stream>>>((const uint*)pred, (const uint*)succ,
                                    (const uint*)same, esz);
  k_pack<<<12288, 256, 0, stream>>>(pred, succ, same, bm, inv, ind, esz);
  k_fuse1<<<320, 256, 0, stream>>>(W_space, W_same, W_mix, T1, T2);
  k_fuse2<<<258, 256, 0, stream>>>(W_enc, b_enc, b_space, b_same, b_mix, W_mix,
                                   T1, T2, UT, cvec);
  k_enc<<<dim3(256, 4), 256, 0, stream>>>(features, UT, cvec, out, eT0, eT1, eT2);
  k_mm<<<768, 256, 0, stream>>>(bm, eT0, eT1, eT2, inv, ind, cvec, P0, P1, P2);
  k_add<<<2048, 256, 0, stream>>>((float4*)out, (const float4*)P0,
                                  (const float4*)P1, (const float4*)P2);
}

// Round 5
// 456.402 us; speedup vs baseline: 12.1770x; 12.1770x over previous
//
#include <hip/hip_runtime.h>
#include <stdint.h>

typedef unsigned int uint;
typedef unsigned short ushort;
typedef unsigned char uchar;
typedef __attribute__((ext_vector_type(8))) short bf16x8;
typedef __attribute__((ext_vector_type(4))) float f32x4;

__device__ __forceinline__ ushort f2bf(float f) {
  uint u = __builtin_bit_cast(uint, f);
  return (ushort)((u + 0x7FFFu + ((u >> 16) & 1u)) >> 16);
}

// ---------------------------------------------------------------------------
// Mask element width: esz stays nonzero if every sampled 4-byte word is in
// {0,1,0x3F800000} (int32/float32 masks); byte masks fail with certainty.
__global__ __launch_bounds__(256) void k_detect(
    const uint* __restrict__ mp, const uint* __restrict__ ms,
    const uint* __restrict__ mt, int* __restrict__ esz) {
  int bid = blockIdx.x;  // 192 blocks: 3 masks x 64 chunks
  const uint* m = (bid < 64) ? mp : (bid < 128) ? ms : mt;
  uint v = m[(size_t)(bid & 63) * 65521 + threadIdx.x];
  if (!(v == 0u || v == 1u || v == 0x3F800000u)) atomicAnd(esz, 0);
}

// ---------------------------------------------------------------------------
// Streaming mask compression: one wave per (mid,row). Reads 8KB (int32) or
// 2KB (byte) coalesced, writes 256B bitmap + inv/ind scalars. BW-bound.
__global__ __launch_bounds__(256) void k_pack(
    const void* __restrict__ mp, const void* __restrict__ ms,
    const void* __restrict__ mt, uint* __restrict__ bm,
    float* __restrict__ inv, float* __restrict__ ind,
    const int* __restrict__ esz_p) {
  const int gid = blockIdx.x * 4 + (threadIdx.x >> 6);  // 49152 rows
  const int lane = threadIdx.x & 63;
  const int mid = gid >> 14;
  const int row = gid & 16383;
  const void* mask = (mid == 0) ? mp : (mid == 1) ? ms : mt;
  const bool is4 = (*esz_p != 0);
  uint w = 0;
  if (is4) {
    const uint* p = (const uint*)mask + (size_t)row * 2048 + lane * 32;
    uint4 v[8];
#pragma unroll
    for (int q = 0; q < 8; ++q) v[q] = *(const uint4*)(p + q * 4);
#pragma unroll
    for (int q = 0; q < 8; ++q) {
      w |= (v[q].x != 0u ? 1u : 0u) << (q * 4 + 0);
      w |= (v[q].y != 0u ? 1u : 0u) << (q * 4 + 1);
      w |= (v[q].z != 0u ? 1u : 0u) << (q * 4 + 2);
      w |= (v[q].w != 0u ? 1u : 0u) << (q * 4 + 3);
    }
  } else {
    const uchar* p = (const uchar*)mask + (size_t)row * 2048 + lane * 32;
    uint4 v0 = *(const uint4*)p;
    uint4 v1 = *(const uint4*)(p + 16);
    uint arr[8] = {v0.x, v0.y, v0.z, v0.w, v1.x, v1.y, v1.z, v1.w};
#pragma unroll
    for (int q = 0; q < 8; ++q)
#pragma unroll
      for (int j = 0; j < 4; ++j)
        w |= (((arr[q] >> (j * 8)) & 0xFFu) ? 1u : 0u) << (q * 4 + j);
  }
  bm[(size_t)gid * 64 + lane] = w;
  int c = __popc(w);
#pragma unroll
  for (int off = 1; off < 64; off <<= 1) c += __shfl_xor(c, off, 64);
  if (lane == 0) {
    inv[gid] = 1.0f / (float)(c > 0 ? c : 1);
    ind[gid] = (c > 0) ? 1.0f : 0.0f;
  }
}

// ---------------------------------------------------------------------------
// Fused-weight stage 1: T1 = W_space @ W_mix[0:128], T2 = W_same @ W_mix[128:256]
__global__ __launch_bounds__(256) void k_fuse1(
    const float* __restrict__ Ws, const float* __restrict__ Wsame,
    const float* __restrict__ Wm, float* __restrict__ T1, float* __restrict__ T2) {
  int idx = blockIdx.x * 256 + threadIdx.x;
  if (idx >= 81920) return;
  int r = idx >> 7, n = idx & 127;
  float s = 0.f;
  if (r < 384) {
    for (int c = 0; c < 128; ++c) s += Ws[r * 128 + c] * Wm[c * 128 + n];
    T1[r * 128 + n] = s;
  } else {
    int rr = r - 384;
    for (int c = 0; c < 128; ++c) s += Wsame[rr * 128 + c] * Wm[(128 + c) * 128 + n];
    T2[rr * 128 + n] = s;
  }
}

// ---------------------------------------------------------------------------
// Stage 2: UT[y][n][k] (bf16) for y=0:origin 1:pred 2:succ 3:same, plus
// cvec[0..3][n] bias vectors (c0 includes all constant paths).
__global__ __launch_bounds__(256) void k_fuse2(
    const float* __restrict__ We, const float* __restrict__ be,
    const float* __restrict__ bs, const float* __restrict__ bsame,
    const float* __restrict__ bm_, const float* __restrict__ Wm,
    const float* __restrict__ T1, const float* __restrict__ T2,
    ushort* __restrict__ UT, float* __restrict__ cvec) {
  int idx = blockIdx.x * 256 + threadIdx.x;
  if (idx < 65536) {
    int y = idx >> 14, n = (idx >> 7) & 127, k = idx & 127;
    float s = 0.f;
    if (y == 0)
      for (int m = 0; m < 128; ++m)
        s += We[k * 512 + m] * (T1[(128 + m) * 128 + n] + T2[m * 128 + n]);
    else if (y == 1)
      for (int m = 0; m < 128; ++m) s += We[k * 512 + 128 + m] * T1[m * 128 + n];
    else if (y == 2)
      for (int m = 0; m < 128; ++m) s += We[k * 512 + 256 + m] * T1[(256 + m) * 128 + n];
    else
      for (int m = 0; m < 128; ++m) s += We[k * 512 + 384 + m] * T2[(128 + m) * 128 + n];
    UT[((size_t)y * 128 + n) * 128 + k] = f2bf(s);
  } else if (idx < 66048) {
    int cid = idx - 65536, cv = cid >> 7, n = cid & 127;
    float s = 0.f;
    if (cv == 0) {
      for (int m = 0; m < 128; ++m)
        s += be[m] * (T1[(128 + m) * 128 + n] + T2[m * 128 + n]);
      for (int c = 0; c < 128; ++c) s += bs[c] * Wm[c * 128 + n];
      for (int c = 0; c < 128; ++c) s += bsame[c] * Wm[(128 + c) * 128 + n];
      s += bm_[n];
    } else if (cv == 1) {
      for (int m = 0; m < 128; ++m) s += be[128 + m] * T1[m * 128 + n];
    } else if (cv == 2) {
      for (int m = 0; m < 128; ++m) s += be[256 + m] * T1[(256 + m) * 128 + n];
    } else {
      for (int m = 0; m < 128; ++m) s += be[384 + m] * T2[(128 + m) * 128 + n];
    }
    cvec[cv * 128 + n] = s;
  }
}

// ---------------------------------------------------------------------------
// Encoder: feat(f32) @ UT[y]. y=0 -> out = origin + c0; y=1..3 -> e'_mid in
// MFMA-B-fragment order (16KB tiles, coalesced stores via LDS transpose).
__global__ __launch_bounds__(256) void k_enc(
    const float* __restrict__ feat, const ushort* __restrict__ UT,
    const float* __restrict__ cvec, float* __restrict__ out,
    ushort* __restrict__ eT0, ushort* __restrict__ eT1, ushort* __restrict__ eT2) {
  __shared__ ushort As[64 * 72];
  __shared__ ushort Bs[128 * 72];
  __shared__ ushort stage[8192];
  const int t = threadIdx.x;
  const int gm0 = blockIdx.x * 64;
  const int y = blockIdx.y;
  const int lane = t & 63, wave = t >> 6;
  const int m0w = (wave >> 1) * 32, n0w = (wave & 1) * 64;
  const int quad = lane >> 4, lr = lane & 15;
  const int am = t >> 2, aq = t & 3;
  const int bn = t >> 1, bh = t & 1;
  f32x4 acc[2][4] = {};
  for (int k0 = 0; k0 < 128; k0 += 64) {
    const float* asrc = feat + (size_t)(gm0 + am) * 128 + k0 + aq * 16;
    float4 f0 = *(const float4*)asrc;
    float4 f1 = *(const float4*)(asrc + 4);
    float4 f2 = *(const float4*)(asrc + 8);
    float4 f3 = *(const float4*)(asrc + 12);
    ushort h[16];
    h[0] = f2bf(f0.x); h[1] = f2bf(f0.y); h[2] = f2bf(f0.z); h[3] = f2bf(f0.w);
    h[4] = f2bf(f1.x); h[5] = f2bf(f1.y); h[6] = f2bf(f1.z); h[7] = f2bf(f1.w);
    h[8] = f2bf(f2.x); h[9] = f2bf(f2.y); h[10] = f2bf(f2.z); h[11] = f2bf(f2.w);
    h[12] = f2bf(f3.x); h[13] = f2bf(f3.y); h[14] = f2bf(f3.z); h[15] = f2bf(f3.w);
    const ushort* bsrc = UT + ((size_t)y * 128 + bn) * 128 + k0 + bh * 32;
    bf16x8 bv0 = *(const bf16x8*)bsrc;
    bf16x8 bv1 = *(const bf16x8*)(bsrc + 8);
    bf16x8 bv2 = *(const bf16x8*)(bsrc + 16);
    bf16x8 bv3 = *(const bf16x8*)(bsrc + 24);
    *(bf16x8*)&As[am * 72 + aq * 16] = *(bf16x8*)&h[0];
    *(bf16x8*)&As[am * 72 + aq * 16 + 8] = *(bf16x8*)&h[8];
    *(bf16x8*)&Bs[bn * 72 + bh * 32] = bv0;
    *(bf16x8*)&Bs[bn * 72 + bh * 32 + 8] = bv1;
    *(bf16x8*)&Bs[bn * 72 + bh * 32 + 16] = bv2;
    *(bf16x8*)&Bs[bn * 72 + bh * 32 + 24] = bv3;
    __syncthreads();
#pragma unroll
    for (int kc = 0; kc < 2; ++kc) {
      bf16x8 a[2], b[4];
#pragma unroll
      for (int i = 0; i < 2; ++i)
        a[i] = *(const bf16x8*)&As[(m0w + i * 16 + lr) * 72 + kc * 32 + quad * 8];
#pragma unroll
      for (int j = 0; j < 4; ++j)
        b[j] = *(const bf16x8*)&Bs[(n0w + j * 16 + lr) * 72 + kc * 32 + quad * 8];
#pragma unroll
      for (int i = 0; i < 2; ++i)
#pragma unroll
        for (int j = 0; j < 4; ++j)
          acc[i][j] = __builtin_amdgcn_mfma_f32_16x16x32_bf16(a[i], b[j], acc[i][j], 0, 0, 0);
    }
    __syncthreads();
  }
  if (y == 0) {
#pragma unroll
    for (int i = 0; i < 2; ++i)
#pragma unroll
      for (int j = 0; j < 4; ++j)
#pragma unroll
        for (int r = 0; r < 4; ++r) {
          int m = gm0 + m0w + i * 16 + quad * 4 + r;
          int n = n0w + j * 16 + lr;
          out[(size_t)m * 128 + n] = acc[i][j][r] + cvec[n];
        }
  } else {
#pragma unroll
    for (int i = 0; i < 2; ++i)
#pragma unroll
      for (int j = 0; j < 4; ++j)
#pragma unroll
        for (int r = 0; r < 4; ++r) {
          int rl = m0w + i * 16 + quad * 4 + r;
          int n = n0w + j * 16 + lr;
          int kc = rl >> 5, qd = (rl >> 3) & 3, e = rl & 7;
          stage[((((n >> 4) * 2 + kc) * 4 + qd) * 16 + (n & 15)) * 8 + e] =
              f2bf(acc[i][j][r]);
        }
    __syncthreads();
    ushort* eT = (y == 1) ? eT0 : (y == 2) ? eT1 : eT2;
    ushort* dst = eT + ((size_t)(gm0 >> 11) * 32 + ((gm0 >> 6) & 31)) * 8192 + t * 32;
    const ushort* src = stage + t * 32;
#pragma unroll
    for (int p = 0; p < 4; ++p)
      *(bf16x8*)(dst + p * 8) = *(const bf16x8*)(src + p * 8);
  }
}

// ---------------------------------------------------------------------------
// Masked-mean GEMM from bitmaps. Bitmap staged to LDS; B-frags from L2 with
// depth-2 prefetch into two STATICALLY-NAMED register arrays (pb0/pb1 —
// dynamic indexing of a register array demotes it to scratch: R4 post-mortem,
// 2.5 GB of scratch traffic). Epilogue: plain coalesced f32 stores.
__global__ __launch_bounds__(256, 3) void k_mm(
    const uint* __restrict__ bm, const ushort* __restrict__ eT0,
    const ushort* __restrict__ eT1, const ushort* __restrict__ eT2,
    const float* __restrict__ inv, const float* __restrict__ ind,
    const float* __restrict__ cvec, float* __restrict__ P0,
    float* __restrict__ P1, float* __restrict__ P2) {
  __shared__ uint sbm[64][68];
  const int t = threadIdx.x;
  const int id = blockIdx.x;
  const int xcd = id & 7, q = id >> 3;
  const int mtile = q & 31, gg = xcd * 3 + (q >> 5);
  const int b = gg & 7, mid = gg >> 3;
  const ushort* eT = (mid == 0) ? eT0 : (mid == 1) ? eT1 : eT2;
  float* Pm = (mid == 0) ? P0 : (mid == 1) ? P1 : P2;
  const float* cm = cvec + (mid + 1) * 128;
  const size_t rowbase = (size_t)b * 2048 + mtile * 64;
  const uint* bmbase = bm + ((size_t)mid * 16384 + rowbase) * 64;
  {  // stage 16KB bitmap: t -> row t>>2, words (t&3)*16 .. +15
    int r = t >> 2, c0 = (t & 3) * 16;
    const uint* src = bmbase + (size_t)r * 64 + c0;
    uint4 v0 = *(const uint4*)src;
    uint4 v1 = *(const uint4*)(src + 4);
    uint4 v2 = *(const uint4*)(src + 8);
    uint4 v3 = *(const uint4*)(src + 12);
    *(uint4*)&sbm[r][c0] = v0;
    *(uint4*)&sbm[r][c0 + 4] = v1;
    *(uint4*)&sbm[r][c0 + 8] = v2;
    *(uint4*)&sbm[r][c0 + 12] = v3;
  }
  const int lane = t & 63, wave = t >> 6;
  const int m0w = (wave >> 1) * 32, n0w = (wave & 1) * 64;
  const int quad = lane >> 4, lr = lane & 15;
  const int jb = n0w >> 4;
  const int r0l = m0w + lr, r1l = r0l + 16;
  const ushort* bbase = eT + (size_t)b * 32 * 8192 + quad * 128 + lr * 8;
  f32x4 acc[2][4] = {};
  bf16x8 pb0[4], pb1[4];
#pragma unroll
  for (int j = 0; j < 4; ++j) {
    pb0[j] = *(const bf16x8*)(bbase + (jb + j) * 1024);          // it=0 (tile0,kc0)
    pb1[j] = *(const bf16x8*)(bbase + 512 + (jb + j) * 1024);    // it=1 (tile0,kc1)
  }
  __syncthreads();

#define MM_STEP(IT, PB)                                                       \
  do {                                                                        \
    const int it_ = (IT);                                                     \
    const uint w0 = sbm[r0l][it_];                                            \
    const uint w1 = sbm[r1l][it_];                                            \
    union { bf16x8 v; uint u[4]; } a0, a1;                                    \
    const uint s0 = w0 >> (quad * 8), s1 = w1 >> (quad * 8);                  \
    _Pragma("unroll")                                                         \
    for (int p = 0; p < 4; ++p) {                                             \
      a0.u[p] = (((s0 >> (2 * p)) & 1u) ? 0x3F80u : 0u) |                     \
                (((s0 >> (2 * p)) & 2u) ? 0x3F800000u : 0u);                  \
      a1.u[p] = (((s1 >> (2 * p)) & 1u) ? 0x3F80u : 0u) |                     \
                (((s1 >> (2 * p)) & 2u) ? 0x3F800000u : 0u);                  \
    }                                                                         \
    _Pragma("unroll")                                                         \
    for (int j = 0; j < 4; ++j) {                                             \
      acc[0][j] = __builtin_amdgcn_mfma_f32_16x16x32_bf16(a0.v, PB[j],        \
                                                          acc[0][j], 0, 0, 0);\
      acc[1][j] = __builtin_amdgcn_mfma_f32_16x16x32_bf16(a1.v, PB[j],        \
                                                          acc[1][j], 0, 0, 0);\
    }                                                                         \
    int itn_ = it_ + 2;                                                       \
    if (itn_ > 63) itn_ = 63;                                                 \
    const ushort* bp_ = bbase + (itn_ >> 1) * 8192 + (itn_ & 1) * 512;        \
    _Pragma("unroll")                                                         \
    for (int j = 0; j < 4; ++j)                                               \
      PB[j] = *(const bf16x8*)(bp_ + (jb + j) * 1024);                        \
  } while (0)

  for (int it2 = 0; it2 < 32; ++it2) {
    MM_STEP(2 * it2, pb0);
    MM_STEP(2 * it2 + 1, pb1);
  }
#undef MM_STEP

  float cmv[4];
#pragma unroll
  for (int j = 0; j < 4; ++j) cmv[j] = cm[n0w + j * 16 + lr];
#pragma unroll
  for (int i = 0; i < 2; ++i)
#pragma unroll
    for (int r = 0; r < 4; ++r) {
      const int ml = m0w + i * 16 + quad * 4 + r;
      const size_t row = rowbase + ml;
      const float iv = inv[(size_t)mid * 16384 + row];
      const float id_ = ind[(size_t)mid * 16384 + row];
#pragma unroll
      for (int j = 0; j < 4; ++j) {
        const int n = n0w + j * 16 + lr;
        Pm[row * 128 + n] = acc[i][j][r] * iv + id_ * cmv[j];
      }
    }
}

// ---------------------------------------------------------------------------
// Final merge: out(base) += P0 + P1 + P2. Pure streaming.
__global__ __launch_bounds__(256) void k_add(
    float4* __restrict__ out, const float4* __restrict__ P0,
    const float4* __restrict__ P1, const float4* __restrict__ P2) {
  const int i = blockIdx.x * 256 + threadIdx.x;  // 524288 float4s
  float4 o = out[i];
  const float4 a = P0[i], b = P1[i], c = P2[i];
  o.x += a.x + b.x + c.x;
  o.y += a.y + b.y + c.y;
  o.z += a.z + b.z + c.z;
  o.w += a.w + b.w + c.w;
  out[i] = o;
}

// ---------------------------------------------------------------------------
extern "C" void kernel_launch(void* const* d_in, const int* in_sizes, int n_in,
                              void* d_out, int out_size, void* d_ws,
                              size_t ws_size, hipStream_t stream) {
  const float* features = (const float*)d_in[0];
  const void* pred = d_in[1];
  const void* succ = d_in[2];
  const void* same = d_in[3];
  const float* W_enc = (const float*)d_in[4];
  const float* b_enc = (const float*)d_in[5];
  const float* W_space = (const float*)d_in[6];
  const float* b_space = (const float*)d_in[7];
  const float* W_same = (const float*)d_in[8];
  const float* b_same = (const float*)d_in[9];
  const float* W_mix = (const float*)d_in[10];
  const float* b_mix = (const float*)d_in[11];
  float* out = (float*)d_out;

  char* wsb = (char*)d_ws;
  ushort* UT = (ushort*)wsb;                          // 128 KB
  float* cvec = (float*)(wsb + 131072);               // 2 KB
  float* T1 = (float*)(wsb + 133120);                 // 192 KB
  float* T2 = (float*)(wsb + 329728);                 // 128 KB
  ushort* eT0 = (ushort*)(wsb + 460800);              // 4 MB each
  ushort* eT1 = (ushort*)(wsb + 460800 + 4194304);
  ushort* eT2 = (ushort*)(wsb + 460800 + 8388608);
  uint* bm = (uint*)(wsb + 13043712);                 // 12 MB bitmaps
  float* inv = (float*)(wsb + 25626624);              // 192 KB
  float* ind = (float*)(wsb + 25823232);              // 192 KB
  float* P0 = (float*)(wsb + 26019840);               // 8 MB each
  float* P1 = (float*)(wsb + 26019840 + 8388608);
  float* P2 = (float*)(wsb + 26019840 + 16777216);
  int* esz = (int*)(wsb + 51185664);

  hipMemsetAsync(esz, 1, 4, stream);
  k_detect<<<192, 256, 0, stream>>>((const uint*)pred, (const uint*)succ,
                                    (const uint*)same, esz);
  k_pack<<<12288, 256, 0, stream>>>(pred, succ, same, bm, inv, ind, esz);
  k_fuse1<<<320, 256, 0, stream>>>(W_space, W_same, W_mix, T1, T2);
  k_fuse2<<<258, 256, 0, stream>>>(W_enc, b_enc, b_space, b_same, b_mix, W_mix,
                                   T1, T2, UT, cvec);
  k_enc<<<dim3(256, 4), 256, 0, stream>>>(features, UT, cvec, out, eT0, eT1, eT2);
  k_mm<<<768, 256, 0, stream>>>(bm, eT0, eT1, eT2, inv, ind, cvec, P0, P1, P2);
  k_add<<<2048, 256, 0, stream>>>((float4*)out, (const float4*)P0,
                                  (const float4*)P1, (const float4*)P2);
}